// Round 12
// baseline (386.389 us; speedup 1.0000x reference)
//
#include <hip/hip_runtime.h>
#include <hip/hip_bf16.h>

#define NN 100000   // nodes
#define NE 1600000  // edges
#define NG 100      // graphs
#define NPG 1000    // nodes per graph
#define CE 16       // edge channels
#define HH 64       // hidden
#define BN_SCALE 0.99999500003749959f  // 1/sqrt(1+1e-5)
#define NB 200          // edge-chunk blocks
#define ECH (NE / NB)   // 8000 edges per chunk
#define NBIN 400        // dst bins: bin = dst/250 (4 bins per graph)
#define NRANGE 12500    // nodes per XCD range

// LESSON (R3): f32 global atomicAdd on gfx950 = near-memory RMW (~35B HBM each).
// LESSON (R5): int global atomics ~40B each -> counting-sort CSR, no atomics.
// LESSON (R6): edge-per-wave-instruction LDS scatter is ~10x slower than
// wave-per-node register accumulation with 8-deep load ILP.
// LESSON (R8): W "register cache" via LDS stays in LDS; use global loads.
// LESSON (R9): un-unrolled load+add loops serialize at L2/L3 latency.
// LESSON (R10): guarded loads (`if(k<hi) v=load`) serialize; clamp+cndmask.
// LESSON (R11): the allocator granted only 84 VGPR despite launch_bounds(,1);
// a 144-float W cache partially demoted to per-node L2 re-loads (~44us of L2
// traffic). Fix: PACK W as bf16 pairs so the whole cache fits the grant.

// ---- phase 1: per-chunk histogram over 400 dst-bins (LDS atomics only) ----
__global__ __launch_bounds__(256) void k_hist(const int* __restrict__ ei,
                                              int* __restrict__ hist) {
  __shared__ int h[NBIN];
  for (int i = threadIdx.x; i < NBIN; i += 256) h[i] = 0;
  __syncthreads();
  int e0 = blockIdx.x * ECH;
  for (int i = threadIdx.x; i < ECH; i += 256) {
    int d = ei[NE + e0 + i];
    atomicAdd(&h[d / 250], 1);
  }
  __syncthreads();
  for (int i = threadIdx.x; i < NBIN; i += 256) hist[blockIdx.x * NBIN + i] = h[i];
}

// ---- phase 2a: per-bin exclusive scan over the 200 chunk-counts ----
__global__ __launch_bounds__(256) void k_scan_a(const int* __restrict__ hist,
                                                int* __restrict__ partial,
                                                int* __restrict__ gtot) {
  __shared__ int sv[256];
  int bin = blockIdx.x, t = threadIdx.x;
  int v = (t < NB) ? hist[t * NBIN + bin] : 0;
  sv[t] = v;
  __syncthreads();
  for (int o = 1; o < 256; o <<= 1) {
    int a = (t >= o) ? sv[t - o] : 0;
    __syncthreads();
    sv[t] += a;
    __syncthreads();
  }
  if (t < NB) partial[t * NBIN + bin] = sv[t] - v;
  if (t == 255) gtot[bin] = sv[255];
}

// ---- phase 2b: exclusive scan of the 400 bin totals -> segment bases ----
__global__ __launch_bounds__(512) void k_scan_b(const int* __restrict__ gtot,
                                                int* __restrict__ gbase) {
  __shared__ int sv[512];
  int t = threadIdx.x;
  int v = (t < NBIN) ? gtot[t] : 0;
  sv[t] = v;
  __syncthreads();
  for (int o = 1; o < 512; o <<= 1) {
    int a = (t >= o) ? sv[t - o] : 0;
    __syncthreads();
    sv[t] += a;
    __syncthreads();
  }
  if (t < NBIN) gbase[t] = sv[t] - v;
  if (t == 511) gbase[NBIN] = sv[511];
}

// ---- phase 3: scatter edges into bin segments (LDS cursors, 1x 8B store) ----
// ebuf[pos] = eid<<32 | dst_local<<10 | src_local   (locals are within-graph)
__global__ __launch_bounds__(256) void k_bfill(const int* __restrict__ ei,
                                               const int* __restrict__ partial,
                                               const int* __restrict__ gbase,
                                               unsigned long long* __restrict__ ebuf) {
  __shared__ int cur[NBIN];
  int b = blockIdx.x;
  for (int i = threadIdx.x; i < NBIN; i += 256)
    cur[i] = gbase[i] + partial[b * NBIN + i];
  __syncthreads();
  int e0 = b * ECH;
  for (int i = threadIdx.x; i < ECH; i += 256) {
    int e = e0 + i;
    int d = ei[NE + e], s = ei[e];
    int bin = d / 250;
    int gb = (bin >> 2) * 1000;
    unsigned long long pk = (unsigned long long)(unsigned)e << 32 |
                            (unsigned)((d - gb) << 10) | (unsigned)(s - gb);
    int pos = atomicAdd(&cur[bin], 1);
    ebuf[pos] = pk;
  }
}

// ---- phase 4: within-bin counting sort by node -> per-node CSR ----
// ebuf2[pos] = eid<<10 | src_local (u32); rowptr[n]..rowptr[n+1]; cnt = deg
__global__ __launch_bounds__(256) void k_nsort(
    const unsigned long long* __restrict__ ebuf, const int* __restrict__ gbase,
    unsigned* __restrict__ ebuf2, int* __restrict__ rowptr,
    int* __restrict__ cnt) {
  __shared__ int h[250];
  __shared__ int cur[250];
  __shared__ int sv[256];
  int bin = blockIdx.x, t = threadIdx.x;
  int nb = bin * 250, lbase = (bin & 3) * 250;
  int lo = gbase[bin], hi = gbase[bin + 1];
  if (t < 250) h[t] = 0;
  __syncthreads();
  for (int i = lo + t; i < hi; i += 256) {
    int dl = (int)((ebuf[i] >> 10) & 1023);
    atomicAdd(&h[dl - lbase], 1);
  }
  __syncthreads();
  int v = (t < 250) ? h[t] : 0;
  sv[t] = v;
  __syncthreads();
  for (int o = 1; o < 256; o <<= 1) {
    int a = (t >= o) ? sv[t - o] : 0;
    __syncthreads();
    sv[t] += a;
    __syncthreads();
  }
  if (t < 250) {
    int base = lo + sv[t] - v;  // exclusive
    rowptr[nb + t] = base;
    cur[t] = base;
    cnt[nb + t] = v;
  }
  if (bin == NBIN - 1 && t == 0) rowptr[NN] = hi;
  __syncthreads();
  for (int i = lo + t; i < hi; i += 256) {
    unsigned long long u = ebuf[i];
    int dl = (int)((u >> 10) & 1023);
    unsigned pk = (unsigned)(u >> 32) << 10 | (unsigned)(u & 1023);
    int pos = atomicAdd(&cur[dl - lbase], 1);
    ebuf2[pos] = pk;
  }
}

// ---- Se[n][c]: wave-per-node, lane = slot(16) x quarter(4), float4 loads ----
#define SEB 25000  // 4 waves/block, wave-per-node; 25000 = 8 * 3125
__global__ __launch_bounds__(256) void k_se3(const unsigned* __restrict__ ebuf2,
                                             const int* __restrict__ rowptr,
                                             const float* __restrict__ ea,
                                             float* __restrict__ Se) {
  int lane = threadIdx.x & 63;
  int slot = lane >> 2;  // edge slot 0..15
  int q = lane & 3;      // row quarter (4 channels)
  int orig = blockIdx.x;
  int blk = (orig & 7) * (SEB / 8) + (orig >> 3);  // XCD-contiguous mapping
  int n0 = blk * 4 + (threadIdx.x >> 6);
  if (n0 >= NN) return;
  int n = __builtin_amdgcn_readfirstlane(n0);
  int lo = rowptr[n], hi = rowptr[n + 1];
  float aA0 = 0.f, aA1 = 0.f, aA2 = 0.f, aA3 = 0.f;
  float aB0 = 0.f, aB1 = 0.f, aB2 = 0.f, aB3 = 0.f;
  for (int k0 = lo; k0 < hi; k0 += 32) {
    int ka = k0 + slot, kb = k0 + 16 + slot;
    int kca = min(ka, NE - 1), kcb = min(kb, NE - 1);
    unsigned eida = ebuf2[kca] >> 10;
    unsigned eidb = ebuf2[kcb] >> 10;
    float4 va = *(const float4*)(ea + (size_t)eida * CE + q * 4);
    float4 vb = *(const float4*)(ea + (size_t)eidb * CE + q * 4);
    bool oka = ka < hi, okb = kb < hi;
    aA0 += oka ? va.x : 0.f;
    aA1 += oka ? va.y : 0.f;
    aA2 += oka ? va.z : 0.f;
    aA3 += oka ? va.w : 0.f;
    aB0 += okb ? vb.x : 0.f;
    aB1 += okb ? vb.y : 0.f;
    aB2 += okb ? vb.z : 0.f;
    aB3 += okb ? vb.w : 0.f;
  }
  float r0 = aA0 + aB0, r1 = aA1 + aB1, r2 = aA2 + aB2, r3 = aA3 + aB3;
#pragma unroll
  for (int o = 4; o < 64; o <<= 1) {  // reduce across the 16 slots
    r0 += __shfl_xor(r0, o);
    r1 += __shfl_xor(r1, o);
    r2 += __shfl_xor(r2, o);
    r3 += __shfl_xor(r3, o);
  }
  if (lane < 4) {  // lane==q holds channels q*4..q*4+3
    float4 w = make_float4(r0, r1, r2, r3);
    *(float4*)(Se + (size_t)n * CE + lane * 4) = w;
  }
}

// ------- per-layer node GEMM: W packed as bf16 pairs in VGPRs (R11) -------
// wij[k] = bf16(Wi[k][lane]) | bf16(Wj[k][lane])<<16 : 64 u32 for BOTH mats.
// y[n][h] = x[n] @ Wj[:,h]; z = deg*(x@Wi + b) + (Se+ones)@We  (bf16 out)
#define GB 1536  // 6 blocks/CU, 24 waves/CU (84-VGPR occupancy ceiling)
template <typename T>
__global__ __launch_bounds__(256, 1) void k_gemm(
    const T* __restrict__ x, const float* __restrict__ W,
    const float* __restrict__ b, const int* __restrict__ cnt,
    const float* __restrict__ Se, __hip_bfloat16* __restrict__ y,
    __hip_bfloat16* __restrict__ z) {
  int lane = threadIdx.x & 63;
  unsigned wij[64];  // packed Wi(lo)|Wj(hi), bf16 truncated
#pragma unroll
  for (int k = 0; k < 64; ++k) {
    unsigned ui = __float_as_uint(W[k * 64 + lane]);
    unsigned uj = __float_as_uint(W[(64 + k) * 64 + lane]);
    wij[k] = (ui >> 16) | (uj & 0xffff0000u);
  }
  unsigned wep[8];  // packed We[2m](lo)|We[2m+1](hi)
  float wesum = 0.f;
#pragma unroll
  for (int m = 0; m < 8; ++m) {
    float w0 = W[(128 + 2 * m) * 64 + lane];
    float w1 = W[(128 + 2 * m + 1) * 64 + lane];
    wep[m] = (__float_as_uint(w0) >> 16) | (__float_as_uint(w1) & 0xffff0000u);
    wesum += __uint_as_float(__float_as_uint(w0) & 0xffff0000u) +
             __uint_as_float(__float_as_uint(w1) & 0xffff0000u);
  }
  float bv = b[lane];
  int xcd = blockIdx.x & 7;
  int wid = (blockIdx.x >> 3) * 4 + (threadIdx.x >> 6);  // 0..767 in range
  int lo = xcd * NRANGE, hi = lo + NRANGE;
  const int stride = (GB / 8) * 4;
  for (int n0 = lo + wid; n0 < hi; n0 += stride) {
    int n = __builtin_amdgcn_readfirstlane(n0);  // wave-uniform -> s_load row
    float xv[64];  // uniform values -> SGPRs
    if constexpr (sizeof(T) == 4) {
      const float* xr = (const float*)x + (size_t)n * HH;
#pragma unroll
      for (int k = 0; k < 64; ++k) xv[k] = xr[k];
    } else {
      const unsigned* xr = (const unsigned*)((const T*)x + (size_t)n * HH);
#pragma unroll
      for (int k2 = 0; k2 < 32; ++k2) {
        unsigned u = xr[k2];
        xv[2 * k2] = __uint_as_float(u << 16);
        xv[2 * k2 + 1] = __uint_as_float(u & 0xffff0000u);
      }
    }
    const float* sr = Se + (size_t)n * CE;
    float a0 = 0.f, a1 = 0.f, a2 = 0.f, a3 = 0.f;  // y accums
    float c0 = 0.f, c1 = 0.f, c2 = 0.f, c3 = 0.f;  // z accums
#pragma unroll
    for (int k = 0; k < 64; k += 4) {
      unsigned p0 = wij[k], p1 = wij[k + 1], p2 = wij[k + 2], p3 = wij[k + 3];
      c0 = fmaf(xv[k], __uint_as_float(p0 << 16), c0);
      a0 = fmaf(xv[k], __uint_as_float(p0 & 0xffff0000u), a0);
      c1 = fmaf(xv[k + 1], __uint_as_float(p1 << 16), c1);
      a1 = fmaf(xv[k + 1], __uint_as_float(p1 & 0xffff0000u), a1);
      c2 = fmaf(xv[k + 2], __uint_as_float(p2 << 16), c2);
      a2 = fmaf(xv[k + 2], __uint_as_float(p2 & 0xffff0000u), a2);
      c3 = fmaf(xv[k + 3], __uint_as_float(p3 << 16), c3);
      a3 = fmaf(xv[k + 3], __uint_as_float(p3 & 0xffff0000u), a3);
    }
    float s0 = 0.f, s1 = 0.f;
#pragma unroll
    for (int m = 0; m < 8; ++m) {
      unsigned pw = wep[m];
      s0 = fmaf(sr[2 * m], __uint_as_float(pw << 16), s0);
      s1 = fmaf(sr[2 * m + 1], __uint_as_float(pw & 0xffff0000u), s1);
    }
    float deg = (float)(cnt[n] + 1);
    y[(size_t)n * HH + lane] = __float2bfloat16((a0 + a1) + (a2 + a3));
    z[(size_t)n * HH + lane] = __float2bfloat16(
        deg * (((c0 + c1) + (c2 + c3)) + bv) + ((s0 + s1) + wesum));
  }
}

// ---- per-layer gather: wave-per-node, register accumulate, 8-deep ILP ----
#define GTB 25000  // 4 waves/block, wave-per-node; 25000 = 8 * 3125
__global__ __launch_bounds__(256) void k_gath3(
    const __hip_bfloat16* __restrict__ y, const __hip_bfloat16* __restrict__ z,
    const unsigned* __restrict__ ebuf2, const int* __restrict__ rowptr,
    const float* __restrict__ gamma, const float* __restrict__ beta,
    __hip_bfloat16* __restrict__ xn, float* __restrict__ emb) {
  int lane = threadIdx.x & 63;
  int orig = blockIdx.x;
  int blk = (orig & 7) * (GTB / 8) + (orig >> 3);  // XCD-contiguous mapping
  int n0 = blk * 4 + (threadIdx.x >> 6);
  if (n0 >= NN) return;
  int n = __builtin_amdgcn_readfirstlane(n0);
  int lo = rowptr[n], hi = rowptr[n + 1];
  int deg = hi - lo;
  int gb = (n / NPG) * NPG;  // graph base node
  const unsigned* cl = ebuf2 + lo;  // wave-uniform
  const __hip_bfloat16* yg = y + (size_t)gb * HH;
  float acc = __bfloat162float(z[(size_t)n * HH + lane]) +
              __bfloat162float(y[(size_t)n * HH + lane]);  // local + self-loop
  int k = 0;
  for (; k + 8 <= deg; k += 8) {
    int s0 = cl[k] & 1023, s1 = cl[k + 1] & 1023;
    int s2 = cl[k + 2] & 1023, s3 = cl[k + 3] & 1023;
    int s4 = cl[k + 4] & 1023, s5 = cl[k + 5] & 1023;
    int s6 = cl[k + 6] & 1023, s7 = cl[k + 7] & 1023;
    float v0 = __bfloat162float(yg[(size_t)s0 * HH + lane]);
    float v1 = __bfloat162float(yg[(size_t)s1 * HH + lane]);
    float v2 = __bfloat162float(yg[(size_t)s2 * HH + lane]);
    float v3 = __bfloat162float(yg[(size_t)s3 * HH + lane]);
    float v4 = __bfloat162float(yg[(size_t)s4 * HH + lane]);
    float v5 = __bfloat162float(yg[(size_t)s5 * HH + lane]);
    float v6 = __bfloat162float(yg[(size_t)s6 * HH + lane]);
    float v7 = __bfloat162float(yg[(size_t)s7 * HH + lane]);
    acc += ((v0 + v1) + (v2 + v3)) + ((v4 + v5) + (v6 + v7));
  }
  for (; k < deg; ++k)
    acc += __bfloat162float(yg[(size_t)(cl[k] & 1023) * HH + lane]);
  acc = fmaxf(acc, 0.f);                            // relu inside MP layer
  acc = gamma[lane] * acc * BN_SCALE + beta[lane];  // eval BN
  acc = fmaxf(acc, 0.f);                            // relu after BN
  xn[(size_t)n * HH + lane] = __float2bfloat16(acc);
  if (n % NPG == 0) emb[(n / NPG) * HH + lane] = acc;  // spec_idx = g*NPG
}

// ---- pool: 400 blocks x 8 waves, 4-deep unrolled; partial[bin][64] f32 ----
__global__ __launch_bounds__(512) void k_pool(const __hip_bfloat16* __restrict__ xf,
                                              float* __restrict__ partial) {
  __shared__ float pp[8][64];
  int bin = blockIdx.x;
  int lane = threadIdx.x & 63, wv = threadIdx.x >> 6;
  const __hip_bfloat16* base = xf + (size_t)bin * 250 * HH;
  float acc = 0.f;
  int i = wv;
  for (; i + 24 < 250; i += 32) {
    float v0 = __bfloat162float(base[(size_t)i * HH + lane]);
    float v1 = __bfloat162float(base[(size_t)(i + 8) * HH + lane]);
    float v2 = __bfloat162float(base[(size_t)(i + 16) * HH + lane]);
    float v3 = __bfloat162float(base[(size_t)(i + 24) * HH + lane]);
    acc += (v0 + v1) + (v2 + v3);
  }
  for (; i < 250; i += 8) acc += __bfloat162float(base[(size_t)i * HH + lane]);
  pp[wv][lane] = acc;
  __syncthreads();
  if (wv == 0) {
    float s = ((pp[0][lane] + pp[1][lane]) + (pp[2][lane] + pp[3][lane])) +
              ((pp[4][lane] + pp[5][lane]) + (pp[6][lane] + pp[7][lane]));
    partial[bin * 64 + lane] = s;
  }
}

// ---------------- readout MLP: ILP-unrolled fc1, parallel fc2 ----------------
__global__ __launch_bounds__(256) void k_final(
    const float* __restrict__ partial, const float* __restrict__ emb,
    const float* __restrict__ nbr, const float* __restrict__ fc1w,
    const float* __restrict__ fc1b, const float* __restrict__ fc2w,
    const float* __restrict__ fc2b, float* __restrict__ out) {
  __shared__ float feats[320];
  __shared__ float r1[256];
  __shared__ float red[4][4];
  int g = blockIdx.x;
  int t = threadIdx.x;
  if (t < 64) {
    const float* pb = partial + 4 * g * 64;
    feats[t] = (pb[t] + pb[64 + t]) + (pb[128 + t] + pb[192 + t]);
    feats[256 + t] = nbr[(size_t)g * HH + t];
  } else {
    int j = t - 64;  // 0..191 -> 3 layer embs
    feats[64 + j] = emb[((size_t)(j >> 6) * NG + g) * HH + (j & 63)];
  }
  __syncthreads();
  float a0 = fc1b[t], a1 = 0.f, a2 = 0.f, a3 = 0.f;
  const float* wp = fc1w + t;
  for (int k = 0; k < 320; k += 8) {  // 8 loads in flight, 4 accumulators
    float w0 = wp[(k + 0) * 256], w1 = wp[(k + 1) * 256];
    float w2 = wp[(k + 2) * 256], w3 = wp[(k + 3) * 256];
    float w4 = wp[(k + 4) * 256], w5 = wp[(k + 5) * 256];
    float w6 = wp[(k + 6) * 256], w7 = wp[(k + 7) * 256];
    a0 = fmaf(feats[k], w0, a0);
    a1 = fmaf(feats[k + 1], w1, a1);
    a2 = fmaf(feats[k + 2], w2, a2);
    a3 = fmaf(feats[k + 3], w3, a3);
    a0 = fmaf(feats[k + 4], w4, a0);
    a1 = fmaf(feats[k + 5], w5, a1);
    a2 = fmaf(feats[k + 6], w6, a2);
    a3 = fmaf(feats[k + 7], w7, a3);
  }
  float rv = fmaxf((a0 + a1) + (a2 + a3), 0.f);
  r1[t] = rv;
  // fc2 parallel: each thread's 4 products, wave-reduce, cross-wave combine
  float p0 = rv * fc2w[t * 4 + 0];
  float p1 = rv * fc2w[t * 4 + 1];
  float p2 = rv * fc2w[t * 4 + 2];
  float p3 = rv * fc2w[t * 4 + 3];
#pragma unroll
  for (int o = 1; o < 64; o <<= 1) {
    p0 += __shfl_xor(p0, o);
    p1 += __shfl_xor(p1, o);
    p2 += __shfl_xor(p2, o);
    p3 += __shfl_xor(p3, o);
  }
  if ((t & 63) == 0) {
    int wv = t >> 6;
    red[wv][0] = p0; red[wv][1] = p1; red[wv][2] = p2; red[wv][3] = p3;
  }
  __syncthreads();
  if (t < 4)
    out[g * 4 + t] = fc2b[t] +
                     ((red[0][t] + red[1][t]) + (red[2][t] + red[3][t]));
}

extern "C" void kernel_launch(void* const* d_in, const int* in_sizes, int n_in,
                              void* d_out, int out_size, void* d_ws, size_t ws_size,
                              hipStream_t stream) {
  const float* x     = (const float*)d_in[0];
  const float* eattr = (const float*)d_in[1];
  const float* nbr   = (const float*)d_in[2];
  const float* W     = (const float*)d_in[3];
  const float* b     = (const float*)d_in[4];
  const float* gamma = (const float*)d_in[5];
  const float* beta  = (const float*)d_in[6];
  const float* fc1w  = (const float*)d_in[7];
  const float* fc1b  = (const float*)d_in[8];
  const float* fc2w  = (const float*)d_in[9];
  const float* fc2b  = (const float*)d_in[10];
  const int*   ei    = (const int*)d_in[11];
  float* out = (float*)d_out;
  (void)in_sizes; (void)n_in; (void)out_size; (void)ws_size;

  char* p = (char*)d_ws;
  size_t off = 0;
  auto alloc = [&](size_t bytes) {
    char* q = p + off;
    off += (bytes + 255) & ~(size_t)255;
    return q;
  };
  int* hist    = (int*)alloc((size_t)NB * NBIN * 4);
  int* partial = (int*)alloc((size_t)NB * NBIN * 4);
  int* gtot    = (int*)alloc((size_t)NBIN * 4);
  int* gbase   = (int*)alloc((size_t)(NBIN + 1) * 4);
  unsigned long long* ebuf = (unsigned long long*)alloc((size_t)NE * 8);
  unsigned* ebuf2 = (unsigned*)alloc((size_t)NE * 4);
  int* rowptr  = (int*)alloc((size_t)(NN + 1) * 4);
  float* Se    = (float*)alloc((size_t)NN * CE * 4);
  int*   cnt   = (int*)alloc((size_t)NN * 4);
  __hip_bfloat16* ybuf = (__hip_bfloat16*)alloc((size_t)NN * HH * 2);
  __hip_bfloat16* zbuf = (__hip_bfloat16*)alloc((size_t)NN * HH * 2);
  __hip_bfloat16* xA   = (__hip_bfloat16*)alloc((size_t)NN * HH * 2);
  __hip_bfloat16* xB   = (__hip_bfloat16*)alloc((size_t)NN * HH * 2);
  float* emb   = (float*)alloc((size_t)3 * NG * HH * 4);
  float* pool  = (float*)alloc((size_t)NBIN * HH * 4);

  // CSR build via two-level counting sort (zero global atomics, no memsets)
  k_hist<<<NB, 256, 0, stream>>>(ei, hist);
  k_scan_a<<<NBIN, 256, 0, stream>>>(hist, partial, gtot);
  k_scan_b<<<1, 512, 0, stream>>>(gtot, gbase);
  k_bfill<<<NB, 256, 0, stream>>>(ei, partial, gbase, ebuf);
  k_nsort<<<NBIN, 256, 0, stream>>>(ebuf, gbase, ebuf2, rowptr, cnt);
  k_se3<<<SEB, 256, 0, stream>>>(ebuf2, rowptr, eattr, Se);

  // layer 0: x (f32) -> xA
  k_gemm<float><<<GB, 256, 0, stream>>>(x, W, b, cnt, Se, ybuf, zbuf);
  k_gath3<<<GTB, 256, 0, stream>>>(ybuf, zbuf, ebuf2, rowptr, gamma, beta, xA, emb);
  // layer 1: xA -> xB
  k_gemm<__hip_bfloat16><<<GB, 256, 0, stream>>>(xA, W + 144 * 64, b + 64, cnt, Se,
                                                 ybuf, zbuf);
  k_gath3<<<GTB, 256, 0, stream>>>(ybuf, zbuf, ebuf2, rowptr, gamma + 64, beta + 64,
                                   xB, emb + NG * HH);
  // layer 2: xB -> xA
  k_gemm<__hip_bfloat16><<<GB, 256, 0, stream>>>(xB, W + 2 * 144 * 64, b + 128, cnt,
                                                 Se, ybuf, zbuf);
  k_gath3<<<GTB, 256, 0, stream>>>(ybuf, zbuf, ebuf2, rowptr, gamma + 128, beta + 128,
                                   xA, emb + 2 * NG * HH);

  k_pool<<<NBIN, 512, 0, stream>>>(xA, pool);
  k_final<<<NG, 256, 0, stream>>>(pool, emb, nbr, fc1w, fc1b, fc2w, fc2b, out);
}

// Round 13
// 273.975 us; speedup vs baseline: 1.4103x; 1.4103x over previous
//
#include <hip/hip_runtime.h>
#include <hip/hip_bf16.h>

#define NN 100000   // nodes
#define NE 1600000  // edges
#define NG 100      // graphs
#define NPG 1000    // nodes per graph
#define CE 16       // edge channels
#define HH 64       // hidden
#define BN_SCALE 0.99999500003749959f  // 1/sqrt(1+1e-5)
#define NB 200          // edge-chunk blocks
#define ECH (NE / NB)   // 8000 edges per chunk
#define NBIN 400        // dst bins: bin = dst/250 (4 bins per graph)
#define NRANGE 12500    // nodes per XCD range

// LESSON (R3): f32 global atomicAdd on gfx950 = near-memory RMW (~35B HBM each).
// LESSON (R5): int global atomics ~40B each -> counting-sort CSR, no atomics.
// LESSON (R6): edge-per-wave-instruction LDS scatter ~10x slower than
// wave-per-node register accumulation with 8-deep load ILP.
// LESSON (R8): W "register cache" via LDS stays in LDS; use global loads.
// LESSON (R9): un-unrolled load+add loops serialize at L2/L3 latency.
// LESSON (R10): guarded loads (`if(k<hi) v=load`) serialize; clamp+cndmask.
// LESSON (R11/R12): allocator targets 84 VGPR (6 waves/SIMD) regardless of
// launch_bounds(,1) — use amdgpu_waves_per_eu to lift. And s_load results
// return OUT-OF-ORDER: any use forces lgkmcnt(0) draining ALL scalar loads,
// so scalar-path streaming cannot pipeline. Node GEMMs belong on MFMA.

typedef __attribute__((ext_vector_type(8))) short bf16x8;
typedef __attribute__((ext_vector_type(4))) float f32x4;
union ABu { bf16x8 f; ushort u[8]; };

__device__ __forceinline__ ushort f2bf_rne(float f) {
  unsigned u = __float_as_uint(f);
  return (ushort)((u + 0x7FFFu + ((u >> 16) & 1u)) >> 16);
}

// ---- phase 1: per-chunk histogram over 400 dst-bins (LDS atomics only) ----
__global__ __launch_bounds__(256) void k_hist(const int* __restrict__ ei,
                                              int* __restrict__ hist) {
  __shared__ int h[NBIN];
  for (int i = threadIdx.x; i < NBIN; i += 256) h[i] = 0;
  __syncthreads();
  int e0 = blockIdx.x * ECH;
  for (int i = threadIdx.x; i < ECH; i += 256) {
    int d = ei[NE + e0 + i];
    atomicAdd(&h[d / 250], 1);
  }
  __syncthreads();
  for (int i = threadIdx.x; i < NBIN; i += 256) hist[blockIdx.x * NBIN + i] = h[i];
}

// ---- phase 2a: per-bin exclusive scan over the 200 chunk-counts ----
__global__ __launch_bounds__(256) void k_scan_a(const int* __restrict__ hist,
                                                int* __restrict__ partial,
                                                int* __restrict__ gtot) {
  __shared__ int sv[256];
  int bin = blockIdx.x, t = threadIdx.x;
  int v = (t < NB) ? hist[t * NBIN + bin] : 0;
  sv[t] = v;
  __syncthreads();
  for (int o = 1; o < 256; o <<= 1) {
    int a = (t >= o) ? sv[t - o] : 0;
    __syncthreads();
    sv[t] += a;
    __syncthreads();
  }
  if (t < NB) partial[t * NBIN + bin] = sv[t] - v;
  if (t == 255) gtot[bin] = sv[255];
}

// ---- phase 2b: exclusive scan of the 400 bin totals -> segment bases ----
__global__ __launch_bounds__(512) void k_scan_b(const int* __restrict__ gtot,
                                                int* __restrict__ gbase) {
  __shared__ int sv[512];
  int t = threadIdx.x;
  int v = (t < NBIN) ? gtot[t] : 0;
  sv[t] = v;
  __syncthreads();
  for (int o = 1; o < 512; o <<= 1) {
    int a = (t >= o) ? sv[t - o] : 0;
    __syncthreads();
    sv[t] += a;
    __syncthreads();
  }
  if (t < NBIN) gbase[t] = sv[t] - v;
  if (t == 511) gbase[NBIN] = sv[511];
}

// ---- phase 3: scatter edges into bin segments (LDS cursors, 1x 8B store) ----
__global__ __launch_bounds__(256) void k_bfill(const int* __restrict__ ei,
                                               const int* __restrict__ partial,
                                               const int* __restrict__ gbase,
                                               unsigned long long* __restrict__ ebuf) {
  __shared__ int cur[NBIN];
  int b = blockIdx.x;
  for (int i = threadIdx.x; i < NBIN; i += 256)
    cur[i] = gbase[i] + partial[b * NBIN + i];
  __syncthreads();
  int e0 = b * ECH;
  for (int i = threadIdx.x; i < ECH; i += 256) {
    int e = e0 + i;
    int d = ei[NE + e], s = ei[e];
    int bin = d / 250;
    int gb = (bin >> 2) * 1000;
    unsigned long long pk = (unsigned long long)(unsigned)e << 32 |
                            (unsigned)((d - gb) << 10) | (unsigned)(s - gb);
    int pos = atomicAdd(&cur[bin], 1);
    ebuf[pos] = pk;
  }
}

// ---- phase 4: within-bin counting sort by node -> per-node CSR ----
__global__ __launch_bounds__(256) void k_nsort(
    const unsigned long long* __restrict__ ebuf, const int* __restrict__ gbase,
    unsigned* __restrict__ ebuf2, int* __restrict__ rowptr,
    int* __restrict__ cnt) {
  __shared__ int h[250];
  __shared__ int cur[250];
  __shared__ int sv[256];
  int bin = blockIdx.x, t = threadIdx.x;
  int nb = bin * 250, lbase = (bin & 3) * 250;
  int lo = gbase[bin], hi = gbase[bin + 1];
  if (t < 250) h[t] = 0;
  __syncthreads();
  for (int i = lo + t; i < hi; i += 256) {
    int dl = (int)((ebuf[i] >> 10) & 1023);
    atomicAdd(&h[dl - lbase], 1);
  }
  __syncthreads();
  int v = (t < 250) ? h[t] : 0;
  sv[t] = v;
  __syncthreads();
  for (int o = 1; o < 256; o <<= 1) {
    int a = (t >= o) ? sv[t - o] : 0;
    __syncthreads();
    sv[t] += a;
    __syncthreads();
  }
  if (t < 250) {
    int base = lo + sv[t] - v;  // exclusive
    rowptr[nb + t] = base;
    cur[t] = base;
    cnt[nb + t] = v;
  }
  if (bin == NBIN - 1 && t == 0) rowptr[NN] = hi;
  __syncthreads();
  for (int i = lo + t; i < hi; i += 256) {
    unsigned long long u = ebuf[i];
    int dl = (int)((u >> 10) & 1023);
    unsigned pk = (unsigned)(u >> 32) << 10 | (unsigned)(u & 1023);
    int pos = atomicAdd(&cur[dl - lbase], 1);
    ebuf2[pos] = pk;
  }
}

// ---- Se: wave-per-node float4 gather; output PACKED BF16 [n][16] ----
#define SEB 25000
__global__ __launch_bounds__(256) void k_se3(const unsigned* __restrict__ ebuf2,
                                             const int* __restrict__ rowptr,
                                             const float* __restrict__ ea,
                                             ushort* __restrict__ Se16) {
  int lane = threadIdx.x & 63;
  int slot = lane >> 2;  // edge slot 0..15
  int q = lane & 3;      // row quarter (4 channels)
  int orig = blockIdx.x;
  int blk = (orig & 7) * (SEB / 8) + (orig >> 3);
  int n0 = blk * 4 + (threadIdx.x >> 6);
  if (n0 >= NN) return;
  int n = __builtin_amdgcn_readfirstlane(n0);
  int lo = rowptr[n], hi = rowptr[n + 1];
  float aA0 = 0.f, aA1 = 0.f, aA2 = 0.f, aA3 = 0.f;
  float aB0 = 0.f, aB1 = 0.f, aB2 = 0.f, aB3 = 0.f;
  for (int k0 = lo; k0 < hi; k0 += 32) {
    int ka = k0 + slot, kb = k0 + 16 + slot;
    int kca = min(ka, NE - 1), kcb = min(kb, NE - 1);
    unsigned eida = ebuf2[kca] >> 10;
    unsigned eidb = ebuf2[kcb] >> 10;
    float4 va = *(const float4*)(ea + (size_t)eida * CE + q * 4);
    float4 vb = *(const float4*)(ea + (size_t)eidb * CE + q * 4);
    bool oka = ka < hi, okb = kb < hi;
    aA0 += oka ? va.x : 0.f;
    aA1 += oka ? va.y : 0.f;
    aA2 += oka ? va.z : 0.f;
    aA3 += oka ? va.w : 0.f;
    aB0 += okb ? vb.x : 0.f;
    aB1 += okb ? vb.y : 0.f;
    aB2 += okb ? vb.z : 0.f;
    aB3 += okb ? vb.w : 0.f;
  }
  float r0 = aA0 + aB0, r1 = aA1 + aB1, r2 = aA2 + aB2, r3 = aA3 + aB3;
#pragma unroll
  for (int o = 4; o < 64; o <<= 1) {
    r0 += __shfl_xor(r0, o);
    r1 += __shfl_xor(r1, o);
    r2 += __shfl_xor(r2, o);
    r3 += __shfl_xor(r3, o);
  }
  if (lane < 4) {
    unsigned lo32 = (unsigned)f2bf_rne(r0) | ((unsigned)f2bf_rne(r1) << 16);
    unsigned hi32 = (unsigned)f2bf_rne(r2) | ((unsigned)f2bf_rne(r3) << 16);
    *(uint2*)(Se16 + (size_t)n * 16 + lane * 4) = make_uint2(lo32, hi32);
  }
}

// ---- x f32 -> bf16 for layer 0 ----
__global__ __launch_bounds__(256) void k_cvt(const float* __restrict__ xin,
                                             ushort* __restrict__ xb) {
  int i = blockIdx.x * 256 + threadIdx.x;  // NN*64/4 = 1.6M float4s
  float4 v = ((const float4*)xin)[i];
  ushort4 o;
  o.x = f2bf_rne(v.x); o.y = f2bf_rne(v.y);
  o.z = f2bf_rne(v.z); o.w = f2bf_rne(v.w);
  ((ushort4*)xb)[i] = o;
}

// ---------------- per-layer node GEMM via MFMA (R12) ----------------
// Per wave: 16-node tile. accM[8] = X@[Wi|Wj] (K=64, 2 mfma per col-tile).
// accS[4] = [Se,1,0..]@[We;wesum] (K=32). z = deg*(accM_i+b)+accS; y = accM_j.
// Fragment layouts (gfx950 16x16x32): elem e <-> k=(e<4?0:16)+4*(lane>>4)+(e&3);
// A row = lane&15, B col = lane&15. C/D: col=lane&15, row=(lane>>4)*4+reg.
#define GEMM_TILES (NN / 16)  // 6250
#define GB 512
__global__ __attribute__((amdgpu_waves_per_eu(2, 4))) __launch_bounds__(256)
void k_gemm(const ushort* __restrict__ x, const float* __restrict__ W,
            const float* __restrict__ b, const int* __restrict__ cnt,
            const ushort* __restrict__ Se16, ushort* __restrict__ y,
            ushort* __restrict__ z) {
  int lane = threadIdx.x & 63;
  int g = lane >> 4, r16 = lane & 15;

  ABu Bm[8][2];
  ABu Bs[4];
  float bias4[4];
#pragma unroll
  for (int t = 0; t < 8; ++t) {
    int col = t * 16 + r16;
    const float* wbase = W + (col < 64 ? 0 : 64 * 64);
    int c64 = col & 63;
#pragma unroll
    for (int h = 0; h < 2; ++h)
#pragma unroll
      for (int e = 0; e < 8; ++e) {
        int k = h * 32 + (e < 4 ? 0 : 16) + 4 * g + (e & 3);
        Bm[t][h].u[e] = f2bf_rne(wbase[k * 64 + c64]);
      }
  }
#pragma unroll
  for (int t = 0; t < 4; ++t) {
    int col = t * 16 + r16;
    float ws = 0.f;
#pragma unroll
    for (int m = 0; m < 16; ++m) ws += W[(128 + m) * 64 + col];
#pragma unroll
    for (int e = 0; e < 8; ++e) {
      int k = (e < 4 ? 0 : 16) + 4 * g + (e & 3);
      float v = (k < 16) ? W[(128 + k) * 64 + col] : (k == 16 ? ws : 0.f);
      Bs[t].u[e] = f2bf_rne(v);
    }
    bias4[t] = b[col];
  }

  int wid = (blockIdx.x << 2) + (threadIdx.x >> 6);
  int nw = GB * 4;
  for (int tt = wid; tt < GEMM_TILES; tt += nw) {
    int nb = tt * 16;
    const ushort* xr = x + (size_t)(nb + r16) * 64;
    ABu A0, A1, AS;
    *(ushort4*)&A0.u[0] = *(const ushort4*)(xr + 4 * g);
    *(ushort4*)&A0.u[4] = *(const ushort4*)(xr + 16 + 4 * g);
    *(ushort4*)&A1.u[0] = *(const ushort4*)(xr + 32 + 4 * g);
    *(ushort4*)&A1.u[4] = *(const ushort4*)(xr + 48 + 4 * g);
    const ushort* sr = Se16 + (size_t)(nb + r16) * 16;
    *(ushort4*)&AS.u[0] = *(const ushort4*)(sr + 4 * g);
    AS.u[4] = (g == 0) ? (ushort)0x3F80 : (ushort)0;  // k==16 -> 1.0
    AS.u[5] = 0; AS.u[6] = 0; AS.u[7] = 0;
    float dq[4];
#pragma unroll
    for (int q = 0; q < 4; ++q) dq[q] = (float)(cnt[nb + 4 * g + q] + 1);

    f32x4 accM[8], accS[4];
#pragma unroll
    for (int t = 0; t < 8; ++t) {
      f32x4 zz = {0.f, 0.f, 0.f, 0.f};
      zz = __builtin_amdgcn_mfma_f32_16x16x32_bf16(A0.f, Bm[t][0].f, zz, 0, 0, 0);
      accM[t] = __builtin_amdgcn_mfma_f32_16x16x32_bf16(A1.f, Bm[t][1].f, zz, 0, 0, 0);
    }
#pragma unroll
    for (int t = 0; t < 4; ++t) {
      f32x4 zz = {0.f, 0.f, 0.f, 0.f};
      accS[t] = __builtin_amdgcn_mfma_f32_16x16x32_bf16(AS.f, Bs[t].f, zz, 0, 0, 0);
    }
#pragma unroll
    for (int q = 0; q < 4; ++q) {
      size_t node = (size_t)(nb + 4 * g + q);
      ushort* zp = z + node * 64 + r16;
      ushort* yp = y + node * 64 + r16;
#pragma unroll
      for (int t = 0; t < 4; ++t) {
        float zv = dq[q] * (accM[t][q] + bias4[t]) + accS[t][q];
        zp[t * 16] = f2bf_rne(zv);
        yp[t * 16] = f2bf_rne(accM[4 + t][q]);
      }
    }
  }
}

// ---- per-layer gather: wave-per-node, register accumulate, 8-deep ILP ----
#define GTB 25000
__global__ __launch_bounds__(256) void k_gath3(
    const __hip_bfloat16* __restrict__ y, const __hip_bfloat16* __restrict__ z,
    const unsigned* __restrict__ ebuf2, const int* __restrict__ rowptr,
    const float* __restrict__ gamma, const float* __restrict__ beta,
    __hip_bfloat16* __restrict__ xn, float* __restrict__ emb) {
  int lane = threadIdx.x & 63;
  int orig = blockIdx.x;
  int blk = (orig & 7) * (GTB / 8) + (orig >> 3);
  int n0 = blk * 4 + (threadIdx.x >> 6);
  if (n0 >= NN) return;
  int n = __builtin_amdgcn_readfirstlane(n0);
  int lo = rowptr[n], hi = rowptr[n + 1];
  int deg = hi - lo;
  int gb = (n / NPG) * NPG;
  const unsigned* cl = ebuf2 + lo;
  const __hip_bfloat16* yg = y + (size_t)gb * HH;
  float acc = __bfloat162float(z[(size_t)n * HH + lane]) +
              __bfloat162float(y[(size_t)n * HH + lane]);
  int k = 0;
  for (; k + 8 <= deg; k += 8) {
    int s0 = cl[k] & 1023, s1 = cl[k + 1] & 1023;
    int s2 = cl[k + 2] & 1023, s3 = cl[k + 3] & 1023;
    int s4 = cl[k + 4] & 1023, s5 = cl[k + 5] & 1023;
    int s6 = cl[k + 6] & 1023, s7 = cl[k + 7] & 1023;
    float v0 = __bfloat162float(yg[(size_t)s0 * HH + lane]);
    float v1 = __bfloat162float(yg[(size_t)s1 * HH + lane]);
    float v2 = __bfloat162float(yg[(size_t)s2 * HH + lane]);
    float v3 = __bfloat162float(yg[(size_t)s3 * HH + lane]);
    float v4 = __bfloat162float(yg[(size_t)s4 * HH + lane]);
    float v5 = __bfloat162float(yg[(size_t)s5 * HH + lane]);
    float v6 = __bfloat162float(yg[(size_t)s6 * HH + lane]);
    float v7 = __bfloat162float(yg[(size_t)s7 * HH + lane]);
    acc += ((v0 + v1) + (v2 + v3)) + ((v4 + v5) + (v6 + v7));
  }
  for (; k < deg; ++k)
    acc += __bfloat162float(yg[(size_t)(cl[k] & 1023) * HH + lane]);
  acc = fmaxf(acc, 0.f);
  acc = gamma[lane] * acc * BN_SCALE + beta[lane];
  acc = fmaxf(acc, 0.f);
  xn[(size_t)n * HH + lane] = __float2bfloat16(acc);
  if (n % NPG == 0) emb[(n / NPG) * HH + lane] = acc;
}

// ---- pool: 400 blocks x 8 waves, 4-deep unrolled; partial[bin][64] f32 ----
__global__ __launch_bounds__(512) void k_pool(const __hip_bfloat16* __restrict__ xf,
                                              float* __restrict__ partial) {
  __shared__ float pp[8][64];
  int bin = blockIdx.x;
  int lane = threadIdx.x & 63, wv = threadIdx.x >> 6;
  const __hip_bfloat16* base = xf + (size_t)bin * 250 * HH;
  float acc = 0.f;
  int i = wv;
  for (; i + 24 < 250; i += 32) {
    float v0 = __bfloat162float(base[(size_t)i * HH + lane]);
    float v1 = __bfloat162float(base[(size_t)(i + 8) * HH + lane]);
    float v2 = __bfloat162float(base[(size_t)(i + 16) * HH + lane]);
    float v3 = __bfloat162float(base[(size_t)(i + 24) * HH + lane]);
    acc += (v0 + v1) + (v2 + v3);
  }
  for (; i < 250; i += 8) acc += __bfloat162float(base[(size_t)i * HH + lane]);
  pp[wv][lane] = acc;
  __syncthreads();
  if (wv == 0) {
    float s = ((pp[0][lane] + pp[1][lane]) + (pp[2][lane] + pp[3][lane])) +
              ((pp[4][lane] + pp[5][lane]) + (pp[6][lane] + pp[7][lane]));
    partial[bin * 64 + lane] = s;
  }
}

// ---------------- readout MLP: ILP-unrolled fc1, parallel fc2 ----------------
__global__ __launch_bounds__(256) void k_final(
    const float* __restrict__ partial, const float* __restrict__ emb,
    const float* __restrict__ nbr, const float* __restrict__ fc1w,
    const float* __restrict__ fc1b, const float* __restrict__ fc2w,
    const float* __restrict__ fc2b, float* __restrict__ out) {
  __shared__ float feats[320];
  __shared__ float r1[256];
  __shared__ float red[4][4];
  int g = blockIdx.x;
  int t = threadIdx.x;
  if (t < 64) {
    const float* pb = partial + 4 * g * 64;
    feats[t] = (pb[t] + pb[64 + t]) + (pb[128 + t] + pb[192 + t]);
    feats[256 + t] = nbr[(size_t)g * HH + t];
  } else {
    int j = t - 64;
    feats[64 + j] = emb[((size_t)(j >> 6) * NG + g) * HH + (j & 63)];
  }
  __syncthreads();
  float a0 = fc1b[t], a1 = 0.f, a2 = 0.f, a3 = 0.f;
  const float* wp = fc1w + t;
  for (int k = 0; k < 320; k += 8) {
    float w0 = wp[(k + 0) * 256], w1 = wp[(k + 1) * 256];
    float w2 = wp[(k + 2) * 256], w3 = wp[(k + 3) * 256];
    float w4 = wp[(k + 4) * 256], w5 = wp[(k + 5) * 256];
    float w6 = wp[(k + 6) * 256], w7 = wp[(k + 7) * 256];
    a0 = fmaf(feats[k], w0, a0);
    a1 = fmaf(feats[k + 1], w1, a1);
    a2 = fmaf(feats[k + 2], w2, a2);
    a3 = fmaf(feats[k + 3], w3, a3);
    a0 = fmaf(feats[k + 4], w4, a0);
    a1 = fmaf(feats[k + 5], w5, a1);
    a2 = fmaf(feats[k + 6], w6, a2);
    a3 = fmaf(feats[k + 7], w7, a3);
  }
  float rv = fmaxf((a0 + a1) + (a2 + a3), 0.f);
  r1[t] = rv;
  float p0 = rv * fc2w[t * 4 + 0];
  float p1 = rv * fc2w[t * 4 + 1];
  float p2 = rv * fc2w[t * 4 + 2];
  float p3 = rv * fc2w[t * 4 + 3];
#pragma unroll
  for (int o = 1; o < 64; o <<= 1) {
    p0 += __shfl_xor(p0, o);
    p1 += __shfl_xor(p1, o);
    p2 += __shfl_xor(p2, o);
    p3 += __shfl_xor(p3, o);
  }
  if ((t & 63) == 0) {
    int wv = t >> 6;
    red[wv][0] = p0; red[wv][1] = p1; red[wv][2] = p2; red[wv][3] = p3;
  }
  __syncthreads();
  if (t < 4)
    out[g * 4 + t] = fc2b[t] +
                     ((red[0][t] + red[1][t]) + (red[2][t] + red[3][t]));
}

extern "C" void kernel_launch(void* const* d_in, const int* in_sizes, int n_in,
                              void* d_out, int out_size, void* d_ws, size_t ws_size,
                              hipStream_t stream) {
  const float* x     = (const float*)d_in[0];
  const float* eattr = (const float*)d_in[1];
  const float* nbr   = (const float*)d_in[2];
  const float* W     = (const float*)d_in[3];
  const float* b     = (const float*)d_in[4];
  const float* gamma = (const float*)d_in[5];
  const float* beta  = (const float*)d_in[6];
  const float* fc1w  = (const float*)d_in[7];
  const float* fc1b  = (const float*)d_in[8];
  const float* fc2w  = (const float*)d_in[9];
  const float* fc2b  = (const float*)d_in[10];
  const int*   ei    = (const int*)d_in[11];
  float* out = (float*)d_out;
  (void)in_sizes; (void)n_in; (void)out_size; (void)ws_size;

  char* p = (char*)d_ws;
  size_t off = 0;
  auto alloc = [&](size_t bytes) {
    char* q = p + off;
    off += (bytes + 255) & ~(size_t)255;
    return q;
  };
  int* hist    = (int*)alloc((size_t)NB * NBIN * 4);
  int* partial = (int*)alloc((size_t)NB * NBIN * 4);
  int* gtot    = (int*)alloc((size_t)NBIN * 4);
  int* gbase   = (int*)alloc((size_t)(NBIN + 1) * 4);
  unsigned long long* ebuf = (unsigned long long*)alloc((size_t)NE * 8);
  unsigned* ebuf2 = (unsigned*)alloc((size_t)NE * 4);
  int* rowptr  = (int*)alloc((size_t)(NN + 1) * 4);
  ushort* Se16 = (ushort*)alloc((size_t)NN * 16 * 2);
  int*   cnt   = (int*)alloc((size_t)NN * 4);
  ushort* xbf  = (ushort*)alloc((size_t)NN * HH * 2);
  ushort* ybuf = (ushort*)alloc((size_t)NN * HH * 2);
  ushort* zbuf = (ushort*)alloc((size_t)NN * HH * 2);
  ushort* xA   = (ushort*)alloc((size_t)NN * HH * 2);
  ushort* xB   = (ushort*)alloc((size_t)NN * HH * 2);
  float* emb   = (float*)alloc((size_t)3 * NG * HH * 4);
  float* pool  = (float*)alloc((size_t)NBIN * HH * 4);

  // CSR build via two-level counting sort (zero global atomics, no memsets)
  k_hist<<<NB, 256, 0, stream>>>(ei, hist);
  k_scan_a<<<NBIN, 256, 0, stream>>>(hist, partial, gtot);
  k_scan_b<<<1, 512, 0, stream>>>(gtot, gbase);
  k_bfill<<<NB, 256, 0, stream>>>(ei, partial, gbase, ebuf);
  k_nsort<<<NBIN, 256, 0, stream>>>(ebuf, gbase, ebuf2, rowptr, cnt);
  k_se3<<<SEB, 256, 0, stream>>>(ebuf2, rowptr, eattr, Se16);
  k_cvt<<<NN * HH / 4 / 256, 256, 0, stream>>>(x, xbf);

  // layer 0: xbf -> xA
  k_gemm<<<GB, 256, 0, stream>>>(xbf, W, b, cnt, Se16, ybuf, zbuf);
  k_gath3<<<GTB, 256, 0, stream>>>((const __hip_bfloat16*)ybuf,
                                   (const __hip_bfloat16*)zbuf, ebuf2, rowptr,
                                   gamma, beta, (__hip_bfloat16*)xA, emb);
  // layer 1: xA -> xB
  k_gemm<<<GB, 256, 0, stream>>>(xA, W + 144 * 64, b + 64, cnt, Se16, ybuf, zbuf);
  k_gath3<<<GTB, 256, 0, stream>>>((const __hip_bfloat16*)ybuf,
                                   (const __hip_bfloat16*)zbuf, ebuf2, rowptr,
                                   gamma + 64, beta + 64, (__hip_bfloat16*)xB,
                                   emb + NG * HH);
  // layer 2: xB -> xA
  k_gemm<<<GB, 256, 0, stream>>>(xB, W + 2 * 144 * 64, b + 128, cnt, Se16, ybuf,
                                 zbuf);
  k_gath3<<<GTB, 256, 0, stream>>>((const __hip_bfloat16*)ybuf,
                                   (const __hip_bfloat16*)zbuf, ebuf2, rowptr,
                                   gamma + 128, beta + 128, (__hip_bfloat16*)xA,
                                   emb + 2 * NG * HH);

  k_pool<<<NBIN, 512, 0, stream>>>((const __hip_bfloat16*)xA, pool);
  k_final<<<NG, 256, 0, stream>>>(pool, emb, nbr, fc1w, fc1b, fc2w, fc2b, out);
}

// Round 14
// 261.277 us; speedup vs baseline: 1.4788x; 1.0486x over previous
//
#include <hip/hip_runtime.h>
#include <hip/hip_bf16.h>

#define NN 100000   // nodes
#define NE 1600000  // edges
#define NG 100      // graphs
#define NPG 1000    // nodes per graph
#define CE 16       // edge channels
#define HH 64       // hidden
#define BN_SCALE 0.99999500003749959f  // 1/sqrt(1+1e-5)
#define NB 512          // edge-chunk blocks (R13: was 200 -> more waves)
#define ECH (NE / NB)   // 3125 edges per chunk
#define NBIN 400        // dst bins: bin = dst/250 (4 bins per graph)
#define NRANGE 12500    // nodes per XCD range

// LESSON (R3): f32 global atomicAdd on gfx950 = near-memory RMW (~35B HBM each).
// LESSON (R5): int global atomics ~40B each -> counting-sort CSR, no atomics.
// LESSON (R6): edge-per-wave-instruction LDS scatter ~10x slower than
// wave-per-node register accumulation with 8-deep load ILP.
// LESSON (R8): W "register cache" via LDS stays in LDS; use global loads.
// LESSON (R9): un-unrolled load+add loops serialize at L2/L3 latency.
// LESSON (R10): guarded loads (`if(k<hi) v=load`) serialize; clamp+cndmask.
// LESSON (R11/R12): allocator targets 84 VGPR; s_load results return
// out-of-order so scalar streaming can't pipeline. Node GEMMs belong on MFMA.
// LESSON (R13): low-block-count build kernels (800-1600 waves device-wide)
// are latency-starved; give every phase >=2k waves.

typedef __attribute__((ext_vector_type(8))) short bf16x8;
typedef __attribute__((ext_vector_type(4))) float f32x4;
union ABu { bf16x8 f; ushort u[8]; };

__device__ __forceinline__ ushort f2bf_rne(float f) {
  unsigned u = __float_as_uint(f);
  return (ushort)((u + 0x7FFFu + ((u >> 16) & 1u)) >> 16);
}

// ---- phase 1: per-chunk histogram over 400 dst-bins (LDS atomics only) ----
__global__ __launch_bounds__(256) void k_hist(const int* __restrict__ ei,
                                              int* __restrict__ hist) {
  __shared__ int h[NBIN];
  for (int i = threadIdx.x; i < NBIN; i += 256) h[i] = 0;
  __syncthreads();
  int e0 = blockIdx.x * ECH;
  for (int i = threadIdx.x; i < ECH; i += 256) {
    int d = ei[NE + e0 + i];
    atomicAdd(&h[d / 250], 1);
  }
  __syncthreads();
  for (int i = threadIdx.x; i < NBIN; i += 256) hist[blockIdx.x * NBIN + i] = h[i];
}

// ---- phase 2a: per-bin exclusive scan over the 512 chunk-counts ----
__global__ __launch_bounds__(512) void k_scan_a(const int* __restrict__ hist,
                                                int* __restrict__ partial,
                                                int* __restrict__ gtot) {
  __shared__ int sv[512];
  int bin = blockIdx.x, t = threadIdx.x;
  int v = (t < NB) ? hist[t * NBIN + bin] : 0;
  sv[t] = v;
  __syncthreads();
  for (int o = 1; o < 512; o <<= 1) {
    int a = (t >= o) ? sv[t - o] : 0;
    __syncthreads();
    sv[t] += a;
    __syncthreads();
  }
  if (t < NB) partial[t * NBIN + bin] = sv[t] - v;
  if (t == 511) gtot[bin] = sv[511];
}

// ---- phase 2b: exclusive scan of the 400 bin totals -> segment bases ----
__global__ __launch_bounds__(512) void k_scan_b(const int* __restrict__ gtot,
                                                int* __restrict__ gbase) {
  __shared__ int sv[512];
  int t = threadIdx.x;
  int v = (t < NBIN) ? gtot[t] : 0;
  sv[t] = v;
  __syncthreads();
  for (int o = 1; o < 512; o <<= 1) {
    int a = (t >= o) ? sv[t - o] : 0;
    __syncthreads();
    sv[t] += a;
    __syncthreads();
  }
  if (t < NBIN) gbase[t] = sv[t] - v;
  if (t == 511) gbase[NBIN] = sv[511];
}

// ---- phase 3: scatter edges into bin segments (LDS cursors, 1x 8B store) ----
__global__ __launch_bounds__(256) void k_bfill(const int* __restrict__ ei,
                                               const int* __restrict__ partial,
                                               const int* __restrict__ gbase,
                                               unsigned long long* __restrict__ ebuf) {
  __shared__ int cur[NBIN];
  int b = blockIdx.x;
  for (int i = threadIdx.x; i < NBIN; i += 256)
    cur[i] = gbase[i] + partial[b * NBIN + i];
  __syncthreads();
  int e0 = b * ECH;
  for (int i = threadIdx.x; i < ECH; i += 256) {
    int e = e0 + i;
    int d = ei[NE + e], s = ei[e];
    int bin = d / 250;
    int gb = (bin >> 2) * 1000;
    unsigned long long pk = (unsigned long long)(unsigned)e << 32 |
                            (unsigned)((d - gb) << 10) | (unsigned)(s - gb);
    int pos = atomicAdd(&cur[bin], 1);
    ebuf[pos] = pk;
  }
}

// ---- phase 4: within-bin counting sort by node -> per-node CSR (1024 thr) ----
__global__ __launch_bounds__(1024) void k_nsort(
    const unsigned long long* __restrict__ ebuf, const int* __restrict__ gbase,
    unsigned* __restrict__ ebuf2, int* __restrict__ rowptr,
    int* __restrict__ cnt) {
  __shared__ int h[250];
  __shared__ int cur[250];
  __shared__ int sv[256];
  int bin = blockIdx.x, t = threadIdx.x;
  int nb = bin * 250, lbase = (bin & 3) * 250;
  int lo = gbase[bin], hi = gbase[bin + 1];
  if (t < 250) h[t] = 0;
  __syncthreads();
  for (int i = lo + t; i < hi; i += 1024) {
    int dl = (int)((ebuf[i] >> 10) & 1023);
    atomicAdd(&h[dl - lbase], 1);
  }
  __syncthreads();
  int v = (t < 250) ? h[t] : 0;
  if (t < 256) sv[t] = v;
  __syncthreads();
  for (int o = 1; o < 256; o <<= 1) {
    int a = (t < 256 && t >= o) ? sv[t - o] : 0;
    __syncthreads();
    if (t < 256) sv[t] += a;
    __syncthreads();
  }
  if (t < 250) {
    int base = lo + sv[t] - v;  // exclusive
    rowptr[nb + t] = base;
    cur[t] = base;
    cnt[nb + t] = v;
  }
  if (bin == NBIN - 1 && t == 0) rowptr[NN] = hi;
  __syncthreads();
  for (int i = lo + t; i < hi; i += 1024) {
    unsigned long long u = ebuf[i];
    int dl = (int)((u >> 10) & 1023);
    unsigned pk = (unsigned)(u >> 32) << 10 | (unsigned)(u & 1023);
    int pos = atomicAdd(&cur[dl - lbase], 1);
    ebuf2[pos] = pk;
  }
}

// ---- Se: wave-per-node float4 gather; output PACKED BF16 [n][16] ----
#define SEB 25000
__global__ __launch_bounds__(256) void k_se3(const unsigned* __restrict__ ebuf2,
                                             const int* __restrict__ rowptr,
                                             const float* __restrict__ ea,
                                             ushort* __restrict__ Se16) {
  int lane = threadIdx.x & 63;
  int slot = lane >> 2;  // edge slot 0..15
  int q = lane & 3;      // row quarter (4 channels)
  int orig = blockIdx.x;
  int blk = (orig & 7) * (SEB / 8) + (orig >> 3);
  int n0 = blk * 4 + (threadIdx.x >> 6);
  if (n0 >= NN) return;
  int n = __builtin_amdgcn_readfirstlane(n0);
  int lo = rowptr[n], hi = rowptr[n + 1];
  float aA0 = 0.f, aA1 = 0.f, aA2 = 0.f, aA3 = 0.f;
  float aB0 = 0.f, aB1 = 0.f, aB2 = 0.f, aB3 = 0.f;
  for (int k0 = lo; k0 < hi; k0 += 32) {
    int ka = k0 + slot, kb = k0 + 16 + slot;
    int kca = min(ka, NE - 1), kcb = min(kb, NE - 1);
    unsigned eida = ebuf2[kca] >> 10;
    unsigned eidb = ebuf2[kcb] >> 10;
    float4 va = *(const float4*)(ea + (size_t)eida * CE + q * 4);
    float4 vb = *(const float4*)(ea + (size_t)eidb * CE + q * 4);
    bool oka = ka < hi, okb = kb < hi;
    aA0 += oka ? va.x : 0.f;
    aA1 += oka ? va.y : 0.f;
    aA2 += oka ? va.z : 0.f;
    aA3 += oka ? va.w : 0.f;
    aB0 += okb ? vb.x : 0.f;
    aB1 += okb ? vb.y : 0.f;
    aB2 += okb ? vb.z : 0.f;
    aB3 += okb ? vb.w : 0.f;
  }
  float r0 = aA0 + aB0, r1 = aA1 + aB1, r2 = aA2 + aB2, r3 = aA3 + aB3;
#pragma unroll
  for (int o = 4; o < 64; o <<= 1) {
    r0 += __shfl_xor(r0, o);
    r1 += __shfl_xor(r1, o);
    r2 += __shfl_xor(r2, o);
    r3 += __shfl_xor(r3, o);
  }
  if (lane < 4) {
    unsigned lo32 = (unsigned)f2bf_rne(r0) | ((unsigned)f2bf_rne(r1) << 16);
    unsigned hi32 = (unsigned)f2bf_rne(r2) | ((unsigned)f2bf_rne(r3) << 16);
    *(uint2*)(Se16 + (size_t)n * 16 + lane * 4) = make_uint2(lo32, hi32);
  }
}

// ---- x f32 -> bf16 for layer 0 ----
__global__ __launch_bounds__(256) void k_cvt(const float* __restrict__ xin,
                                             ushort* __restrict__ xb) {
  int i = blockIdx.x * 256 + threadIdx.x;
  float4 v = ((const float4*)xin)[i];
  ushort4 o;
  o.x = f2bf_rne(v.x); o.y = f2bf_rne(v.y);
  o.z = f2bf_rne(v.z); o.w = f2bf_rne(v.w);
  ((ushort4*)xb)[i] = o;
}

// ---------------- per-layer node GEMM via MFMA (R12) ----------------
// Per wave: 16-node tile. accM[8] = X@[Wi|Wj] (K=64). accS[4] = [Se,1]@[We;ws].
// Layouts: A/B elem e <-> k=(e<4?0:16)+4*(lane>>4)+(e&3); C/D col=lane&15,
// row=(lane>>4)*4+reg.
#define GEMM_TILES (NN / 16)  // 6250
#define GB 512
__global__ __attribute__((amdgpu_waves_per_eu(2, 4))) __launch_bounds__(256)
void k_gemm(const ushort* __restrict__ x, const float* __restrict__ W,
            const float* __restrict__ b, const int* __restrict__ cnt,
            const ushort* __restrict__ Se16, ushort* __restrict__ y,
            ushort* __restrict__ z) {
  int lane = threadIdx.x & 63;
  int g = lane >> 4, r16 = lane & 15;

  ABu Bm[8][2];
  ABu Bs[4];
  float bias4[4];
#pragma unroll
  for (int t = 0; t < 8; ++t) {
    int col = t * 16 + r16;
    const float* wbase = W + (col < 64 ? 0 : 64 * 64);
    int c64 = col & 63;
#pragma unroll
    for (int h = 0; h < 2; ++h)
#pragma unroll
      for (int e = 0; e < 8; ++e) {
        int k = h * 32 + (e < 4 ? 0 : 16) + 4 * g + (e & 3);
        Bm[t][h].u[e] = f2bf_rne(wbase[k * 64 + c64]);
      }
  }
#pragma unroll
  for (int t = 0; t < 4; ++t) {
    int col = t * 16 + r16;
    float ws = 0.f;
#pragma unroll
    for (int m = 0; m < 16; ++m) ws += W[(128 + m) * 64 + col];
#pragma unroll
    for (int e = 0; e < 8; ++e) {
      int k = (e < 4 ? 0 : 16) + 4 * g + (e & 3);
      float v = (k < 16) ? W[(128 + k) * 64 + col] : (k == 16 ? ws : 0.f);
      Bs[t].u[e] = f2bf_rne(v);
    }
    bias4[t] = b[col];
  }

  int wid = (blockIdx.x << 2) + (threadIdx.x >> 6);
  int nw = GB * 4;
  for (int tt = wid; tt < GEMM_TILES; tt += nw) {
    int nb = tt * 16;
    const ushort* xr = x + (size_t)(nb + r16) * 64;
    ABu A0, A1, AS;
    *(ushort4*)&A0.u[0] = *(const ushort4*)(xr + 4 * g);
    *(ushort4*)&A0.u[4] = *(const ushort4*)(xr + 16 + 4 * g);
    *(ushort4*)&A1.u[0] = *(const ushort4*)(xr + 32 + 4 * g);
    *(ushort4*)&A1.u[4] = *(const ushort4*)(xr + 48 + 4 * g);
    const ushort* sr = Se16 + (size_t)(nb + r16) * 16;
    *(ushort4*)&AS.u[0] = *(const ushort4*)(sr + 4 * g);
    AS.u[4] = (g == 0) ? (ushort)0x3F80 : (ushort)0;  // k==16 -> 1.0
    AS.u[5] = 0; AS.u[6] = 0; AS.u[7] = 0;
    float dq[4];
#pragma unroll
    for (int q = 0; q < 4; ++q) dq[q] = (float)(cnt[nb + 4 * g + q] + 1);

    f32x4 accM[8], accS[4];
#pragma unroll
    for (int t = 0; t < 8; ++t) {
      f32x4 zz = {0.f, 0.f, 0.f, 0.f};
      zz = __builtin_amdgcn_mfma_f32_16x16x32_bf16(A0.f, Bm[t][0].f, zz, 0, 0, 0);
      accM[t] = __builtin_amdgcn_mfma_f32_16x16x32_bf16(A1.f, Bm[t][1].f, zz, 0, 0, 0);
    }
#pragma unroll
    for (int t = 0; t < 4; ++t) {
      f32x4 zz = {0.f, 0.f, 0.f, 0.f};
      accS[t] = __builtin_amdgcn_mfma_f32_16x16x32_bf16(AS.f, Bs[t].f, zz, 0, 0, 0);
    }
#pragma unroll
    for (int q = 0; q < 4; ++q) {
      size_t node = (size_t)(nb + 4 * g + q);
      ushort* zp = z + node * 64 + r16;
      ushort* yp = y + node * 64 + r16;
#pragma unroll
      for (int t = 0; t < 4; ++t) {
        float zv = dq[q] * (accM[t][q] + bias4[t]) + accS[t][q];
        zp[t * 16] = f2bf_rne(zv);
        yp[t * 16] = f2bf_rne(accM[4 + t][q]);
      }
    }
  }
}

// ---- per-layer gather: wave-per-node, register accumulate, 8-deep ILP ----
#define GTB 25000
__global__ __launch_bounds__(256) void k_gath3(
    const __hip_bfloat16* __restrict__ y, const __hip_bfloat16* __restrict__ z,
    const unsigned* __restrict__ ebuf2, const int* __restrict__ rowptr,
    const float* __restrict__ gamma, const float* __restrict__ beta,
    __hip_bfloat16* __restrict__ xn, float* __restrict__ emb) {
  int lane = threadIdx.x & 63;
  int orig = blockIdx.x;
  int blk = (orig & 7) * (GTB / 8) + (orig >> 3);
  int n0 = blk * 4 + (threadIdx.x >> 6);
  if (n0 >= NN) return;
  int n = __builtin_amdgcn_readfirstlane(n0);
  int lo = rowptr[n], hi = rowptr[n + 1];
  int deg = hi - lo;
  int gb = (n / NPG) * NPG;
  const unsigned* cl = ebuf2 + lo;
  const __hip_bfloat16* yg = y + (size_t)gb * HH;
  float acc = __bfloat162float(z[(size_t)n * HH + lane]) +
              __bfloat162float(y[(size_t)n * HH + lane]);
  int k = 0;
  for (; k + 8 <= deg; k += 8) {
    int s0 = cl[k] & 1023, s1 = cl[k + 1] & 1023;
    int s2 = cl[k + 2] & 1023, s3 = cl[k + 3] & 1023;
    int s4 = cl[k + 4] & 1023, s5 = cl[k + 5] & 1023;
    int s6 = cl[k + 6] & 1023, s7 = cl[k + 7] & 1023;
    float v0 = __bfloat162float(yg[(size_t)s0 * HH + lane]);
    float v1 = __bfloat162float(yg[(size_t)s1 * HH + lane]);
    float v2 = __bfloat162float(yg[(size_t)s2 * HH + lane]);
    float v3 = __bfloat162float(yg[(size_t)s3 * HH + lane]);
    float v4 = __bfloat162float(yg[(size_t)s4 * HH + lane]);
    float v5 = __bfloat162float(yg[(size_t)s5 * HH + lane]);
    float v6 = __bfloat162float(yg[(size_t)s6 * HH + lane]);
    float v7 = __bfloat162float(yg[(size_t)s7 * HH + lane]);
    acc += ((v0 + v1) + (v2 + v3)) + ((v4 + v5) + (v6 + v7));
  }
  for (; k < deg; ++k)
    acc += __bfloat162float(yg[(size_t)(cl[k] & 1023) * HH + lane]);
  acc = fmaxf(acc, 0.f);
  acc = gamma[lane] * acc * BN_SCALE + beta[lane];
  acc = fmaxf(acc, 0.f);
  xn[(size_t)n * HH + lane] = __float2bfloat16(acc);
  if (n % NPG == 0) emb[(n / NPG) * HH + lane] = acc;
}

// ---- pool: 400 blocks x 8 waves, 4-deep unrolled; partial[bin][64] f32 ----
__global__ __launch_bounds__(512) void k_pool(const __hip_bfloat16* __restrict__ xf,
                                              float* __restrict__ partial) {
  __shared__ float pp[8][64];
  int bin = blockIdx.x;
  int lane = threadIdx.x & 63, wv = threadIdx.x >> 6;
  const __hip_bfloat16* base = xf + (size_t)bin * 250 * HH;
  float acc = 0.f;
  int i = wv;
  for (; i + 24 < 250; i += 32) {
    float v0 = __bfloat162float(base[(size_t)i * HH + lane]);
    float v1 = __bfloat162float(base[(size_t)(i + 8) * HH + lane]);
    float v2 = __bfloat162float(base[(size_t)(i + 16) * HH + lane]);
    float v3 = __bfloat162float(base[(size_t)(i + 24) * HH + lane]);
    acc += (v0 + v1) + (v2 + v3);
  }
  for (; i < 250; i += 8) acc += __bfloat162float(base[(size_t)i * HH + lane]);
  pp[wv][lane] = acc;
  __syncthreads();
  if (wv == 0) {
    float s = ((pp[0][lane] + pp[1][lane]) + (pp[2][lane] + pp[3][lane])) +
              ((pp[4][lane] + pp[5][lane]) + (pp[6][lane] + pp[7][lane]));
    partial[bin * 64 + lane] = s;
  }
}

// ---------------- readout MLP: ILP-unrolled fc1, parallel fc2 ----------------
__global__ __launch_bounds__(256) void k_final(
    const float* __restrict__ partial, const float* __restrict__ emb,
    const float* __restrict__ nbr, const float* __restrict__ fc1w,
    const float* __restrict__ fc1b, const float* __restrict__ fc2w,
    const float* __restrict__ fc2b, float* __restrict__ out) {
  __shared__ float feats[320];
  __shared__ float r1[256];
  __shared__ float red[4][4];
  int g = blockIdx.x;
  int t = threadIdx.x;
  if (t < 64) {
    const float* pb = partial + 4 * g * 64;
    feats[t] = (pb[t] + pb[64 + t]) + (pb[128 + t] + pb[192 + t]);
    feats[256 + t] = nbr[(size_t)g * HH + t];
  } else {
    int j = t - 64;
    feats[64 + j] = emb[((size_t)(j >> 6) * NG + g) * HH + (j & 63)];
  }
  __syncthreads();
  float a0 = fc1b[t], a1 = 0.f, a2 = 0.f, a3 = 0.f;
  const float* wp = fc1w + t;
  for (int k = 0; k < 320; k += 8) {
    float w0 = wp[(k + 0) * 256], w1 = wp[(k + 1) * 256];
    float w2 = wp[(k + 2) * 256], w3 = wp[(k + 3) * 256];
    float w4 = wp[(k + 4) * 256], w5 = wp[(k + 5) * 256];
    float w6 = wp[(k + 6) * 256], w7 = wp[(k + 7) * 256];
    a0 = fmaf(feats[k], w0, a0);
    a1 = fmaf(feats[k + 1], w1, a1);
    a2 = fmaf(feats[k + 2], w2, a2);
    a3 = fmaf(feats[k + 3], w3, a3);
    a0 = fmaf(feats[k + 4], w4, a0);
    a1 = fmaf(feats[k + 5], w5, a1);
    a2 = fmaf(feats[k + 6], w6, a2);
    a3 = fmaf(feats[k + 7], w7, a3);
  }
  float rv = fmaxf((a0 + a1) + (a2 + a3), 0.f);
  r1[t] = rv;
  float p0 = rv * fc2w[t * 4 + 0];
  float p1 = rv * fc2w[t * 4 + 1];
  float p2 = rv * fc2w[t * 4 + 2];
  float p3 = rv * fc2w[t * 4 + 3];
#pragma unroll
  for (int o = 1; o < 64; o <<= 1) {
    p0 += __shfl_xor(p0, o);
    p1 += __shfl_xor(p1, o);
    p2 += __shfl_xor(p2, o);
    p3 += __shfl_xor(p3, o);
  }
  if ((t & 63) == 0) {
    int wv = t >> 6;
    red[wv][0] = p0; red[wv][1] = p1; red[wv][2] = p2; red[wv][3] = p3;
  }
  __syncthreads();
  if (t < 4)
    out[g * 4 + t] = fc2b[t] +
                     ((red[0][t] + red[1][t]) + (red[2][t] + red[3][t]));
}

extern "C" void kernel_launch(void* const* d_in, const int* in_sizes, int n_in,
                              void* d_out, int out_size, void* d_ws, size_t ws_size,
                              hipStream_t stream) {
  const float* x     = (const float*)d_in[0];
  const float* eattr = (const float*)d_in[1];
  const float* nbr   = (const float*)d_in[2];
  const float* W     = (const float*)d_in[3];
  const float* b     = (const float*)d_in[4];
  const float* gamma = (const float*)d_in[5];
  const float* beta  = (const float*)d_in[6];
  const float* fc1w  = (const float*)d_in[7];
  const float* fc1b  = (const float*)d_in[8];
  const float* fc2w  = (const float*)d_in[9];
  const float* fc2b  = (const float*)d_in[10];
  const int*   ei    = (const int*)d_in[11];
  float* out = (float*)d_out;
  (void)in_sizes; (void)n_in; (void)out_size; (void)ws_size;

  char* p = (char*)d_ws;
  size_t off = 0;
  auto alloc = [&](size_t bytes) {
    char* q = p + off;
    off += (bytes + 255) & ~(size_t)255;
    return q;
  };
  int* hist    = (int*)alloc((size_t)NB * NBIN * 4);
  int* partial = (int*)alloc((size_t)NB * NBIN * 4);
  int* gtot    = (int*)alloc((size_t)NBIN * 4);
  int* gbase   = (int*)alloc((size_t)(NBIN + 1) * 4);
  unsigned long long* ebuf = (unsigned long long*)alloc((size_t)NE * 8);
  unsigned* ebuf2 = (unsigned*)alloc((size_t)NE * 4);
  int* rowptr  = (int*)alloc((size_t)(NN + 1) * 4);
  ushort* Se16 = (ushort*)alloc((size_t)NN * 16 * 2);
  int*   cnt   = (int*)alloc((size_t)NN * 4);
  ushort* xbf  = (ushort*)alloc((size_t)NN * HH * 2);
  ushort* ybuf = (ushort*)alloc((size_t)NN * HH * 2);
  ushort* zbuf = (ushort*)alloc((size_t)NN * HH * 2);
  ushort* xA   = (ushort*)alloc((size_t)NN * HH * 2);
  ushort* xB   = (ushort*)alloc((size_t)NN * HH * 2);
  float* emb   = (float*)alloc((size_t)3 * NG * HH * 4);
  float* pool  = (float*)alloc((size_t)NBIN * HH * 4);

  // CSR build via two-level counting sort (zero global atomics, no memsets)
  k_hist<<<NB, 256, 0, stream>>>(ei, hist);
  k_scan_a<<<NBIN, 512, 0, stream>>>(hist, partial, gtot);
  k_scan_b<<<1, 512, 0, stream>>>(gtot, gbase);
  k_bfill<<<NB, 256, 0, stream>>>(ei, partial, gbase, ebuf);
  k_nsort<<<NBIN, 1024, 0, stream>>>(ebuf, gbase, ebuf2, rowptr, cnt);
  k_se3<<<SEB, 256, 0, stream>>>(ebuf2, rowptr, eattr, Se16);
  k_cvt<<<NN * HH / 4 / 256, 256, 0, stream>>>(x, xbf);

  // layer 0: xbf -> xA
  k_gemm<<<GB, 256, 0, stream>>>(xbf, W, b, cnt, Se16, ybuf, zbuf);
  k_gath3<<<GTB, 256, 0, stream>>>((const __hip_bfloat16*)ybuf,
                                   (const __hip_bfloat16*)zbuf, ebuf2, rowptr,
                                   gamma, beta, (__hip_bfloat16*)xA, emb);
  // layer 1: xA -> xB
  k_gemm<<<GB, 256, 0, stream>>>(xA, W + 144 * 64, b + 64, cnt, Se16, ybuf, zbuf);
  k_gath3<<<GTB, 256, 0, stream>>>((const __hip_bfloat16*)ybuf,
                                   (const __hip_bfloat16*)zbuf, ebuf2, rowptr,
                                   gamma + 64, beta + 64, (__hip_bfloat16*)xB,
                                   emb + NG * HH);
  // layer 2: xB -> xA
  k_gemm<<<GB, 256, 0, stream>>>(xB, W + 2 * 144 * 64, b + 128, cnt, Se16, ybuf,
                                 zbuf);
  k_gath3<<<GTB, 256, 0, stream>>>((const __hip_bfloat16*)ybuf,
                                   (const __hip_bfloat16*)zbuf, ebuf2, rowptr,
                                   gamma + 128, beta + 128, (__hip_bfloat16*)xA,
                                   emb + 2 * NG * HH);

  k_pool<<<NBIN, 512, 0, stream>>>((const __hip_bfloat16*)xA, pool);
  k_final<<<NG, 256, 0, stream>>>(pool, emb, nbr, fc1w, fc1b, fc2w, fc2b, out);
}